// Round 12
// baseline (144.164 us; speedup 1.0000x reference)
//
#include <hip/hip_runtime.h>
#include <math.h>

// Problem constants
#define B_  4
#define N_  170
#define T_  96
#define D_  256
#define H_  8
#define HD_ 32
#define BN_ (B_*N_)       // 680 (bn) blocks
#define WSZ (D_*D_)       // 65536 per weight matrix

typedef short  bf16x8 __attribute__((ext_vector_type(8)));
typedef float  f32x4  __attribute__((ext_vector_type(4)));

// ---- LDS map (bytes). All tiles use 256B sub-planes: [..][kgl][lr][16B] ----
// X region: [ks 0..7][rt 0..5][kgl 0..3] planes -> also P scratch & O planes
#define XB   0
// K: [h][rt 0..5][kg 0..3] planes       (element (h, kg, t, j))
#define KB   49152
// q planes (same layout as K) then V: [h][s2 0..2][n2 0..1][kg 0..3] planes
#define VB   98304
#define LDSZ 147456

__device__ __forceinline__ ushort to_bf16(float x)
{
    uint u = __builtin_bit_cast(uint, x);
    u += 0x8000u;                      // round-half-up
    return (ushort)(u >> 16);
}

__device__ __forceinline__ uint pack2(float x0, float x1)
{
    return (uint)to_bf16(x0) | ((uint)to_bf16(x1) << 16);
}

__device__ __forceinline__ uint4 pack8(float4 a0, float4 a1)
{
    uint4 r;
    r.x = pack2(a0.x, a0.y); r.y = pack2(a0.z, a0.w);
    r.z = pack2(a1.x, a1.y); r.w = pack2(a1.z, a1.w);
    return r;
}

#define MFMA(a, b, c) __builtin_amdgcn_mfma_f32_16x16x32_bf16((a), (b), (c), 0, 0, 0)

// ---------------------------------------------------------------------------
// Kernel 0: W prep. W[col][k] fp32 -> single ROUNDED bf16, chunked layout
// [k/8][col][8] per matrix. Wq gets 1/sqrt(32) folded in. 0=Wq 1=Wk 2=Wv 3=Wo.
// ---------------------------------------------------------------------------
__global__ __launch_bounds__(256)
void splitw_kernel(const float* __restrict__ Wq, const float* __restrict__ Wk,
                   const float* __restrict__ Wv, const float* __restrict__ Wo,
                   ushort* __restrict__ whi)
{
    const int gid = blockIdx.x * 256 + threadIdx.x;   // 32768 chunks
    const int mat = gid >> 13;
    const int rem = gid & 8191;
    const int col = rem >> 5;
    const int kc  = rem & 31;
    const float* W = (mat == 0) ? Wq : (mat == 1) ? Wk : (mat == 2) ? Wv : Wo;
    const float s  = (mat == 0) ? 0.17677669529663687f : 1.0f;
    const float* p = W + (size_t)col * D_ + kc * 8;
    float4 a0 = *(const float4*)p;
    float4 a1 = *(const float4*)(p + 4);
    a0.x *= s; a0.y *= s; a0.z *= s; a0.w *= s;
    a1.x *= s; a1.y *= s; a1.z *= s; a1.w *= s;
    const size_t off = (size_t)mat * WSZ + ((size_t)kc * 256 + col) * 8;
    *(uint4*)(whi + off) = pack8(a0, a1);
}

// ---------------------------------------------------------------------------
// Mega kernel: one block per bn. 1024 threads = 16 waves, 4/SIMD.
// amdgpu_waves_per_eu(4,4): LDS (147KB) already limits to 1 block/CU = 4
// waves/EU, so force the compiler to TARGET 4 waves/EU -> 128-VGPR budget,
// which lets the 16 W fragments (64 VGPR) stay preloaded.
// GEMM partition: wave = (dp = wv>>1, th = wv&1) owns d-tiles {2dp, 2dp+1}
// and t-tiles {3th..3th+2} -> each X-fragment LDS read feeds 2 MFMAs
// (halves GEMM LDS-read traffic). W fragments for the NEXT GEMM are loaded
// one phase ahead into a single reused register set (consumption ended a
// phase earlier -> no ping-pong needed). Attention: head h = dp, row-half
// th; K fragments hoisted out of the j-loop (3x reuse).
// ---------------------------------------------------------------------------
__global__ __launch_bounds__(1024)
__attribute__((amdgpu_waves_per_eu(4, 4)))
void mega_kernel(const float* __restrict__ Xq, const float* __restrict__ Xk,
                 const float* __restrict__ Xv, const ushort* __restrict__ W,
                 const float* __restrict__ bq, const float* __restrict__ bk,
                 const float* __restrict__ bv, const float* __restrict__ bo,
                 float* __restrict__ out)
{
    __shared__ __align__(16) char lds[LDSZ];

    const int bn   = blockIdx.x;
    const int tid  = threadIdx.x;
    const int wv   = tid >> 6;       // 0..15
    const int lane = tid & 63;
    const int lr   = lane & 15;
    const int kgl  = lane >> 4;
    const int dp   = wv >> 1;        // d-tile pair / attention head
    const int th   = wv & 1;         // t-half
    const int ib   = th * 3;         // attention irow base
    const size_t xoff = (size_t)bn * T_ * D_;

    // staging chunk coords: 3 chunks/thread (chunk = 8 elems)
    int srow[3], skc[3]; uint saddr[3];
    #pragma unroll
    for (int c = 0; c < 3; c++) {
        const int cc = tid + c * 1024;
        const int row = cc % 96, kc = cc / 96;
        srow[c] = row; skc[c] = kc;
        saddr[c] = (uint)(((((kc >> 2) * 6 + (row >> 4)) * 4 + (kc & 3)) * 256)
                          + (row & 15) * 16);
    }

    bf16x8 wf0[8], wf1[8];   // W fragments for the two owned d-tiles (64 VGPR)

#define LOADW(matbase) do { \
        _Pragma("unroll") \
        for (int ks_ = 0; ks_ < 8; ks_++) { \
            wf0[ks_] = *(const bf16x8*)((matbase) + ((size_t)(ks_*4+kgl)*256 + (dp*2+0)*16 + lr)*8); \
            wf1[ks_] = *(const bf16x8*)((matbase) + ((size_t)(ks_*4+kgl)*256 + (dp*2+1)*16 + lr)*8); \
        } \
    } while (0)

    // ---- stage Xq -> X planes (bf16); preload Wq fragments ----
    #pragma unroll
    for (int c = 0; c < 3; c++) {
        const float* p = Xq + xoff + srow[c] * D_ + skc[c] * 8;
        float4 a0 = *(const float4*)p, a1 = *(const float4*)(p + 4);
        *(uint4*)(lds + XB + saddr[c]) = pack8(a0, a1);
    }
    LOADW(W);
    __syncthreads();                               // (1)

    // ---- prefetch Xk into regs (flies under q-GEMM) ----
    float4 pf[6];
    #pragma unroll
    for (int c = 0; c < 3; c++) {
        const float* p = Xk + xoff + srow[c] * D_ + skc[c] * 8;
        pf[2*c] = *(const float4*)p; pf[2*c+1] = *(const float4*)(p + 4);
    }

    // ---- q^T GEMM: M = d (2 tiles), N = t (3 tiles). col t = lr, row d ----
    {
        f32x4 acc[2][3];
        #pragma unroll
        for (int u = 0; u < 2; u++)
            #pragma unroll
            for (int v = 0; v < 3; v++) acc[u][v] = (f32x4)0.f;
        #pragma unroll
        for (int ks = 0; ks < 8; ks++)
            #pragma unroll
            for (int v = 0; v < 3; v++) {
                bf16x8 xb = *(const bf16x8*)(lds + XB + ((ks*6 + th*3 + v)*4+kgl)*256 + lr*16);
                acc[0][v] = MFMA(wf0[ks], xb, acc[0][v]);
                acc[1][v] = MFMA(wf1[ks], xb, acc[1][v]);
            }
        // epilogue: + s*bq -> bf16 q-planes (K-style layout in V region), h = dp
        const float qs = 0.17677669529663687f;
        #pragma unroll
        for (int u = 0; u < 2; u++) {
            const int mt = dp*2 + u;
            const int kg = u*2 + (kgl >> 1);
            float4 b4 = *(const float4*)(bq + mt*16 + kgl*4);
            #pragma unroll
            for (int v = 0; v < 3; v++) {
                const int nt = th*3 + v;
                ushort4 o;
                o.x = to_bf16(acc[u][v][0] + b4.x*qs);
                o.y = to_bf16(acc[u][v][1] + b4.y*qs);
                o.z = to_bf16(acc[u][v][2] + b4.z*qs);
                o.w = to_bf16(acc[u][v][3] + b4.w*qs);
                *(ushort4*)(lds + VB + ((dp*6+nt)*4+kg)*256 + lr*16 + (kgl&1)*8) = o;
            }
        }
    }
    __syncthreads();                               // (2)

    // ---- write Xk planes; pull q frags; prefetch Xv; preload Wk ----
    #pragma unroll
    for (int c = 0; c < 3; c++)
        *(uint4*)(lds + XB + saddr[c]) = pack8(pf[2*c], pf[2*c+1]);
    bf16x8 qf[3];
    #pragma unroll
    for (int j = 0; j < 3; j++)
        qf[j] = *(const bf16x8*)(lds + VB + ((dp*6 + ib + j)*4 + kgl)*256 + lr*16);
    #pragma unroll
    for (int c = 0; c < 3; c++) {
        const float* p = Xv + xoff + srow[c] * D_ + skc[c] * 8;
        pf[2*c] = *(const float4*)p; pf[2*c+1] = *(const float4*)(p + 4);
    }
    LOADW(W + WSZ);
    __syncthreads();                               // (3)

    // ---- k^T GEMM -> K planes ----
    {
        f32x4 acc[2][3];
        #pragma unroll
        for (int u = 0; u < 2; u++)
            #pragma unroll
            for (int v = 0; v < 3; v++) acc[u][v] = (f32x4)0.f;
        #pragma unroll
        for (int ks = 0; ks < 8; ks++)
            #pragma unroll
            for (int v = 0; v < 3; v++) {
                bf16x8 xb = *(const bf16x8*)(lds + XB + ((ks*6 + th*3 + v)*4+kgl)*256 + lr*16);
                acc[0][v] = MFMA(wf0[ks], xb, acc[0][v]);
                acc[1][v] = MFMA(wf1[ks], xb, acc[1][v]);
            }
        #pragma unroll
        for (int u = 0; u < 2; u++) {
            const int mt = dp*2 + u;
            const int kg = u*2 + (kgl >> 1);
            float4 b4 = *(const float4*)(bk + mt*16 + kgl*4);
            #pragma unroll
            for (int v = 0; v < 3; v++) {
                const int nt = th*3 + v;
                ushort4 o;
                o.x = to_bf16(acc[u][v][0] + b4.x);
                o.y = to_bf16(acc[u][v][1] + b4.y);
                o.z = to_bf16(acc[u][v][2] + b4.z);
                o.w = to_bf16(acc[u][v][3] + b4.w);
                *(ushort4*)(lds + KB + ((dp*6+nt)*4+kg)*256 + lr*16 + (kgl&1)*8) = o;
            }
        }
    }
    __syncthreads();                               // (4)

    // ---- write Xv planes; preload Wv ----
    #pragma unroll
    for (int c = 0; c < 3; c++)
        *(uint4*)(lds + XB + saddr[c]) = pack8(pf[2*c], pf[2*c+1]);
    LOADW(W + 2*WSZ);
    __syncthreads();                               // (5)

    // ---- v GEMM (normal): M = t (3 tiles), N = d (2 tiles) -> V planes ----
    {
        f32x4 av[2][3];
        #pragma unroll
        for (int u = 0; u < 2; u++)
            #pragma unroll
            for (int v = 0; v < 3; v++) av[u][v] = (f32x4)0.f;
        #pragma unroll
        for (int ks = 0; ks < 8; ks++)
            #pragma unroll
            for (int v = 0; v < 3; v++) {
                bf16x8 xa = *(const bf16x8*)(lds + XB + ((ks*6 + th*3 + v)*4+kgl)*256 + lr*16);
                av[0][v] = MFMA(xa, wf0[ks], av[0][v]);
                av[1][v] = MFMA(xa, wf1[ks], av[1][v]);
            }
        // epilogue: d-col tile dp*2+u -> head dp, hd-half u; row t = mt*16+kgl*4+r
        #pragma unroll
        for (int u = 0; u < 2; u++) {
            const float bvv = bv[(dp*2+u)*16 + lr];
            #pragma unroll
            for (int v = 0; v < 3; v++) {
                const int mt = th*3 + v;
                const int kvkg = mt*2 + (kgl >> 1);
                const int s2 = kvkg >> 2, kgv = kvkg & 3;
                ushort4 o;
                o.x = to_bf16(av[u][v][0] + bvv);
                o.y = to_bf16(av[u][v][1] + bvv);
                o.z = to_bf16(av[u][v][2] + bvv);
                o.w = to_bf16(av[u][v][3] + bvv);
                *(ushort4*)(lds + VB + (((dp*3+s2)*2+u)*4+kgv)*256 + lr*16 + (kgl&1)*8) = o;
            }
        }
    }
    __syncthreads();                               // (6)

    // ---- attention: head dp, 3 q-row tiles; K frags hoisted (3x reuse);
    //      swapped QK^T, in-reg softmax, P via per-wave 3KB scratch, PV ----
    f32x4 oacc[3][2];
    #pragma unroll
    for (int j = 0; j < 3; j++) { oacc[j][0] = (f32x4)0.f; oacc[j][1] = (f32x4)0.f; }
    {
        char* sw = lds + XB + wv * 3072;           // 12 planes x 256B
        bf16x8 kf[6];
        #pragma unroll
        for (int mt = 0; mt < 6; mt++)
            kf[mt] = *(const bf16x8*)(lds + KB + ((dp*6+mt)*4+kgl)*256 + lr*16);
        #pragma unroll
        for (int j = 0; j < 3; j++) {
            f32x4 s[6];
            #pragma unroll
            for (int mt = 0; mt < 6; mt++)
                s[mt] = MFMA(kf[mt], qf[j], (f32x4)0.f);   // rows kv, col q = lr
            float mx = s[0][0];
            #pragma unroll
            for (int mt = 0; mt < 6; mt++)
                #pragma unroll
                for (int r = 0; r < 4; r++) mx = fmaxf(mx, s[mt][r]);
            mx = fmaxf(mx, __shfl_xor(mx, 16));
            mx = fmaxf(mx, __shfl_xor(mx, 32));
            float sum = 0.f;
            #pragma unroll
            for (int mt = 0; mt < 6; mt++)
                #pragma unroll
                for (int r = 0; r < 4; r++) {
                    float e = __expf(s[mt][r] - mx);
                    s[mt][r] = e; sum += e;
                }
            sum += __shfl_xor(sum, 16);
            sum += __shfl_xor(sum, 32);
            const float inv = 1.f / sum;
            #pragma unroll
            for (int mt = 0; mt < 6; mt++) {
                uint2 u2;
                u2.x = pack2(s[mt][0]*inv, s[mt][1]*inv);
                u2.y = pack2(s[mt][2]*inv, s[mt][3]*inv);
                *(uint2*)(sw + (mt*2 + (kgl>>1))*256 + lr*16 + (kgl&1)*8) = u2;
            }
            #pragma unroll
            for (int s2 = 0; s2 < 3; s2++) {
                bf16x8 pa = *(const bf16x8*)(sw + (s2*4+kgl)*256 + lr*16);
                #pragma unroll
                for (int n2 = 0; n2 < 2; n2++) {
                    bf16x8 vf = *(const bf16x8*)(lds + VB + (((dp*3+s2)*2+n2)*4+kgl)*256 + lr*16);
                    oacc[j][n2] = MFMA(pa, vf, oacc[j][n2]);
                }
            }
        }
    }
    // ---- preload Wo (hides under O-write + barriers) ----
    LOADW(W + 3*WSZ);
    __syncthreads();                               // (7) scratch dead

    // ---- O -> O planes (X layout), bf16 ----
    #pragma unroll
    for (int j = 0; j < 3; j++)
        #pragma unroll
        for (int n2 = 0; n2 < 2; n2++) {
            const int dcol = dp*32 + n2*16 + lr;
            const int kc   = dcol >> 3;            // 0..31
            const int irow = ib + j;
            char* base = lds + XB + (((kc>>2)*6 + irow)*4 + (kc&3))*256 + (dcol&7)*2;
            #pragma unroll
            for (int r = 0; r < 4; r++)
                *(ushort*)(base + (kgl*4+r)*16) = to_bf16(oacc[j][n2][r]);
        }
    __syncthreads();                               // (8)

    // ---- wo GEMM: M = t (3 tiles), N = d (2 tiles) -> d_out fp32 + bo ----
    {
        f32x4 a2[2][3];
        #pragma unroll
        for (int u = 0; u < 2; u++)
            #pragma unroll
            for (int v = 0; v < 3; v++) a2[u][v] = (f32x4)0.f;
        #pragma unroll
        for (int ks = 0; ks < 8; ks++)
            #pragma unroll
            for (int v = 0; v < 3; v++) {
                bf16x8 oa = *(const bf16x8*)(lds + XB + ((ks*6 + th*3 + v)*4+kgl)*256 + lr*16);
                a2[0][v] = MFMA(oa, wf0[ks], a2[0][v]);
                a2[1][v] = MFMA(oa, wf1[ks], a2[1][v]);
            }
        #pragma unroll
        for (int u = 0; u < 2; u++) {
            const int col = (dp*2+u)*16 + lr;
            const float bod = bo[col];
            #pragma unroll
            for (int v = 0; v < 3; v++) {
                const int mt = th*3 + v;
                #pragma unroll
                for (int r = 0; r < 4; r++) {
                    const int t = mt*16 + kgl*4 + r;
                    out[((size_t)(bn*T_ + t))*D_ + col] = a2[u][v][r] + bod;
                }
            }
        }
    }
#undef LOADW
}

// ---------------------------------------------------------------------------
extern "C" void kernel_launch(void* const* d_in, const int* in_sizes, int n_in,
                              void* d_out, int out_size, void* d_ws, size_t ws_size,
                              hipStream_t stream)
{
    const float* query = (const float*)d_in[0];
    const float* key   = (const float*)d_in[1];
    const float* value = (const float*)d_in[2];
    // d_in[3..5]: pattern_matrix, Wp, bp -- mathematically a no-op (mask == 1)
    const float* Wq = (const float*)d_in[6];
    const float* bq = (const float*)d_in[7];
    const float* Wk = (const float*)d_in[8];
    const float* bk = (const float*)d_in[9];
    const float* Wv = (const float*)d_in[10];
    const float* bv = (const float*)d_in[11];
    const float* Wo = (const float*)d_in[12];
    const float* bo = (const float*)d_in[13];

    float*  out = (float*)d_out;
    ushort* whi = (ushort*)d_ws;   // 4 matrices, chunked bf16: 512 KB

    splitw_kernel<<<dim3(128), 256, 0, stream>>>(Wq, Wk, Wv, Wo, whi);
    mega_kernel<<<dim3(BN_), 1024, 0, stream>>>(
        query, key, value, whi, bq, bk, bv, bo, out);
}

// Round 14
// 102.167 us; speedup vs baseline: 1.4111x; 1.4111x over previous
//
#include <hip/hip_runtime.h>
#include <math.h>

// Problem constants
#define B_  4
#define N_  170
#define T_  96
#define D_  256
#define H_  8
#define HD_ 32
#define BN_ (B_*N_)       // 680 (bn) blocks
#define WSZ (D_*D_)       // 65536 per weight matrix

typedef short  bf16x8 __attribute__((ext_vector_type(8)));
typedef float  f32x4  __attribute__((ext_vector_type(4)));

// ---- LDS map (bytes). All tiles use 256B sub-planes: [..][kgl][lr][16B] ----
// Region lifetimes (one barrier between every last-read and first-write):
//   XB: Xq (P0-P1) -> Xv (P2-P3) -> P scratch (P4) -> O planes (P5-P6)
//   KB: Xk (P1-P2) -> K planes (P3-P4)
//   VB: q planes (P1-P2) -> V planes (P3-P4)
#define XB   0
#define KB   49152
#define VB   98304
#define LDSZ 147456

__device__ __forceinline__ ushort to_bf16(float x)
{
    uint u = __builtin_bit_cast(uint, x);
    u += 0x8000u;                      // round-half-up
    return (ushort)(u >> 16);
}

__device__ __forceinline__ uint pack2(float x0, float x1)
{
    return (uint)to_bf16(x0) | ((uint)to_bf16(x1) << 16);
}

__device__ __forceinline__ uint4 pack8(float4 a0, float4 a1)
{
    uint4 r;
    r.x = pack2(a0.x, a0.y); r.y = pack2(a0.z, a0.w);
    r.z = pack2(a1.x, a1.y); r.w = pack2(a1.z, a1.w);
    return r;
}

#define MFMA(a, b, c) __builtin_amdgcn_mfma_f32_16x16x32_bf16((a), (b), (c), 0, 0, 0)

// ---------------------------------------------------------------------------
// Kernel 0: W prep. W[col][k] fp32 -> single ROUNDED bf16, chunked layout
// [k/8][col][8] per matrix. Wq gets 1/sqrt(32) folded in. 0=Wq 1=Wk 2=Wv 3=Wo.
// ---------------------------------------------------------------------------
__global__ __launch_bounds__(256)
void splitw_kernel(const float* __restrict__ Wq, const float* __restrict__ Wk,
                   const float* __restrict__ Wv, const float* __restrict__ Wo,
                   ushort* __restrict__ whi)
{
    const int gid = blockIdx.x * 256 + threadIdx.x;   // 32768 chunks
    const int mat = gid >> 13;
    const int rem = gid & 8191;
    const int col = rem >> 5;
    const int kc  = rem & 31;
    const float* W = (mat == 0) ? Wq : (mat == 1) ? Wk : (mat == 2) ? Wv : Wo;
    const float s  = (mat == 0) ? 0.17677669529663687f : 1.0f;
    const float* p = W + (size_t)col * D_ + kc * 8;
    float4 a0 = *(const float4*)p;
    float4 a1 = *(const float4*)(p + 4);
    a0.x *= s; a0.y *= s; a0.z *= s; a0.w *= s;
    a1.x *= s; a1.y *= s; a1.z *= s; a1.w *= s;
    const size_t off = (size_t)mat * WSZ + ((size_t)kc * 256 + col) * 8;
    *(uint4*)(whi + off) = pack8(a0, a1);
}

// ---------------------------------------------------------------------------
// Mega kernel: one block per bn. 1024 threads = 16 waves. R9-verbatim math
// (1 d-tile x 6 t-tiles per wave in GEMMs; attention head h = wv>>1, row-half
// wv&1) with a region-rotation schedule: staging writes always co-run with a
// GEMM phase targeting a DIFFERENT region. 6 barriers total (was 8).
//   P0: stage Xq->XB; pf Xk                                  | bar
//   P1: write Xk->KB; pf Xv; q-GEMM(XB) + q-epi->VB          | bar
//   P2: write Xv->XB; qf pull(VB); k-GEMM(KB)                | bar
//   P3: k-epi->KB; v-GEMM(XB) + v-epi->VB                    | bar
//   P4: attention (KB k-planes, VB V-planes, XB P-scratch)   | bar
//   P5: O->XB planes                                         | bar
//   P6: wo-GEMM(XB) -> out
// ---------------------------------------------------------------------------
__global__ __launch_bounds__(1024)
void mega_kernel(const float* __restrict__ Xq, const float* __restrict__ Xk,
                 const float* __restrict__ Xv, const ushort* __restrict__ W,
                 const float* __restrict__ bq, const float* __restrict__ bk,
                 const float* __restrict__ bv, const float* __restrict__ bo,
                 float* __restrict__ out)
{
    __shared__ __align__(16) char lds[LDSZ];

    const int bn   = blockIdx.x;
    const int tid  = threadIdx.x;
    const int wv   = tid >> 6;       // 0..15
    const int lane = tid & 63;
    const int lr   = lane & 15;
    const int kgl  = lane >> 4;
    const int h    = wv >> 1;        // attention head for this wave
    const int ib   = (wv & 1) * 3;   // attention irow base
    const size_t xoff = (size_t)bn * T_ * D_;

    // staging chunk coords: 3 chunks/thread (chunk = 8 elems)
    int srow[3], skc[3]; uint saddr[3];
    #pragma unroll
    for (int c = 0; c < 3; c++) {
        const int cc = tid + c * 1024;
        const int row = cc % 96, kc = cc / 96;
        srow[c] = row; skc[c] = kc;
        saddr[c] = (uint)(((((kc >> 2) * 6 + (row >> 4)) * 4 + (kc & 3)) * 256)
                          + (row & 15) * 16);
    }

    // ---- P0: stage Xq -> XB planes (bf16); prefetch Xk into regs ----
    #pragma unroll
    for (int c = 0; c < 3; c++) {
        const float* p = Xq + xoff + srow[c] * D_ + skc[c] * 8;
        float4 a0 = *(const float4*)p, a1 = *(const float4*)(p + 4);
        *(uint4*)(lds + XB + saddr[c]) = pack8(a0, a1);
    }
    float4 pf[6];
    #pragma unroll
    for (int c = 0; c < 3; c++) {
        const float* p = Xk + xoff + srow[c] * D_ + skc[c] * 8;
        pf[2*c] = *(const float4*)p; pf[2*c+1] = *(const float4*)(p + 4);
    }
    __syncthreads();                               // (0)

    // ---- P1: write Xk -> KB; prefetch Xv; q-GEMM(XB) + q-epi -> VB ----
    #pragma unroll
    for (int c = 0; c < 3; c++)
        *(uint4*)(lds + KB + saddr[c]) = pack8(pf[2*c], pf[2*c+1]);
    #pragma unroll
    for (int c = 0; c < 3; c++) {
        const float* p = Xv + xoff + srow[c] * D_ + skc[c] * 8;
        pf[2*c] = *(const float4*)p; pf[2*c+1] = *(const float4*)(p + 4);
    }
    {
        bf16x8 wf[8];
        #pragma unroll
        for (int ks = 0; ks < 8; ks++)
            wf[ks] = *(const bf16x8*)(W + ((size_t)(ks*4+kgl)*256 + wv*16 + lr)*8);
        f32x4 acc[6];
        #pragma unroll
        for (int nt = 0; nt < 6; nt++) acc[nt] = (f32x4)0.f;
        #pragma unroll
        for (int ks = 0; ks < 8; ks++)
            #pragma unroll
            for (int nt = 0; nt < 6; nt++) {
                bf16x8 xb = *(const bf16x8*)(lds + XB + ((ks*6+nt)*4+kgl)*256 + lr*16);
                acc[nt] = MFMA(wf[ks], xb, acc[nt]);
            }
        // q epilogue: + s*bq -> bf16 q-planes in VB (K-style layout)
        const float qs = 0.17677669529663687f;
        const int kg = (wv & 1)*2 + (kgl >> 1);
        float4 b4 = *(const float4*)(bq + wv*16 + kgl*4);
        #pragma unroll
        for (int nt = 0; nt < 6; nt++) {
            ushort4 o;
            o.x = to_bf16(acc[nt][0] + b4.x*qs);
            o.y = to_bf16(acc[nt][1] + b4.y*qs);
            o.z = to_bf16(acc[nt][2] + b4.z*qs);
            o.w = to_bf16(acc[nt][3] + b4.w*qs);
            *(ushort4*)(lds + VB + ((h*6+nt)*4+kg)*256 + lr*16 + (kgl&1)*8) = o;
        }
    }
    __syncthreads();                               // (1)

    // ---- P2: write Xv -> XB; qf pull(VB); k-GEMM(KB) ----
    #pragma unroll
    for (int c = 0; c < 3; c++)
        *(uint4*)(lds + XB + saddr[c]) = pack8(pf[2*c], pf[2*c+1]);
    bf16x8 qf[3];
    #pragma unroll
    for (int j = 0; j < 3; j++)
        qf[j] = *(const bf16x8*)(lds + VB + ((h*6 + ib + j)*4 + kgl)*256 + lr*16);
    f32x4 kacc[6];
    {
        const ushort* Wk = W + WSZ;
        bf16x8 wf[8];
        #pragma unroll
        for (int ks = 0; ks < 8; ks++)
            wf[ks] = *(const bf16x8*)(Wk + ((size_t)(ks*4+kgl)*256 + wv*16 + lr)*8);
        #pragma unroll
        for (int nt = 0; nt < 6; nt++) kacc[nt] = (f32x4)0.f;
        #pragma unroll
        for (int ks = 0; ks < 8; ks++)
            #pragma unroll
            for (int nt = 0; nt < 6; nt++) {
                bf16x8 xb = *(const bf16x8*)(lds + KB + ((ks*6+nt)*4+kgl)*256 + lr*16);
                kacc[nt] = MFMA(wf[ks], xb, kacc[nt]);
            }
    }
    __syncthreads();                               // (2)

    // ---- P3: k-epi -> KB (Xk dead); v-GEMM(XB) + v-epi -> VB (q dead) ----
    {
        const int kg = (wv & 1)*2 + (kgl >> 1);
        float4 b4 = *(const float4*)(bk + wv*16 + kgl*4);
        #pragma unroll
        for (int nt = 0; nt < 6; nt++) {
            ushort4 o;
            o.x = to_bf16(kacc[nt][0] + b4.x);
            o.y = to_bf16(kacc[nt][1] + b4.y);
            o.z = to_bf16(kacc[nt][2] + b4.z);
            o.w = to_bf16(kacc[nt][3] + b4.w);
            *(ushort4*)(lds + KB + ((h*6+nt)*4+kg)*256 + lr*16 + (kgl&1)*8) = o;
        }
    }
    {
        const ushort* Wv = W + 2*WSZ;
        bf16x8 wf[8];
        #pragma unroll
        for (int ks = 0; ks < 8; ks++)
            wf[ks] = *(const bf16x8*)(Wv + ((size_t)(ks*4+kgl)*256 + wv*16 + lr)*8);
        f32x4 av[6];
        #pragma unroll
        for (int mt = 0; mt < 6; mt++) av[mt] = (f32x4)0.f;
        #pragma unroll
        for (int ks = 0; ks < 8; ks++)
            #pragma unroll
            for (int mt = 0; mt < 6; mt++) {
                bf16x8 xa = *(const bf16x8*)(lds + XB + ((ks*6+mt)*4+kgl)*256 + lr*16);
                av[mt] = MFMA(xa, wf[ks], av[mt]);
            }
        // v epilogue: d-col tile wv -> head h, hd-half n2v; row t = mt*16+kgl*4+r
        const int n2v = wv & 1;
        const float bvv = bv[wv*16 + lr];
        #pragma unroll
        for (int mt = 0; mt < 6; mt++) {
            const int kvkg = mt*2 + (kgl >> 1);
            const int s2 = kvkg >> 2, kgv = kvkg & 3;
            ushort4 o;
            o.x = to_bf16(av[mt][0] + bvv);
            o.y = to_bf16(av[mt][1] + bvv);
            o.z = to_bf16(av[mt][2] + bvv);
            o.w = to_bf16(av[mt][3] + bvv);
            *(ushort4*)(lds + VB + (((h*3+s2)*2+n2v)*4+kgv)*256 + lr*16 + (kgl&1)*8) = o;
        }
    }
    __syncthreads();                               // (3)

    // ---- P4: attention. head h, 3 q-row tiles; swapped QK^T, in-reg
    //      softmax, P via per-wave 3KB scratch in XB (Xv dead), PV ----
    f32x4 oacc[3][2];
    #pragma unroll
    for (int j = 0; j < 3; j++) { oacc[j][0] = (f32x4)0.f; oacc[j][1] = (f32x4)0.f; }
    {
        char* sw = lds + XB + wv * 3072;           // 12 planes x 256B
        #pragma unroll
        for (int j = 0; j < 3; j++) {
            f32x4 s[6];
            #pragma unroll
            for (int mt = 0; mt < 6; mt++) {
                bf16x8 kf = *(const bf16x8*)(lds + KB + ((h*6+mt)*4+kgl)*256 + lr*16);
                s[mt] = MFMA(kf, qf[j], (f32x4)0.f);   // rows kv, col q = lr
            }
            float mx = s[0][0];
            #pragma unroll
            for (int mt = 0; mt < 6; mt++)
                #pragma unroll
                for (int r = 0; r < 4; r++) mx = fmaxf(mx, s[mt][r]);
            mx = fmaxf(mx, __shfl_xor(mx, 16));
            mx = fmaxf(mx, __shfl_xor(mx, 32));
            float sum = 0.f;
            #pragma unroll
            for (int mt = 0; mt < 6; mt++)
                #pragma unroll
                for (int r = 0; r < 4; r++) {
                    float e = __expf(s[mt][r] - mx);
                    s[mt][r] = e; sum += e;
                }
            sum += __shfl_xor(sum, 16);
            sum += __shfl_xor(sum, 32);
            const float inv = 1.f / sum;
            #pragma unroll
            for (int mt = 0; mt < 6; mt++) {
                uint2 u2;
                u2.x = pack2(s[mt][0]*inv, s[mt][1]*inv);
                u2.y = pack2(s[mt][2]*inv, s[mt][3]*inv);
                *(uint2*)(sw + (mt*2 + (kgl>>1))*256 + lr*16 + (kgl&1)*8) = u2;
            }
            #pragma unroll
            for (int s2 = 0; s2 < 3; s2++) {
                bf16x8 pa = *(const bf16x8*)(sw + (s2*4+kgl)*256 + lr*16);
                #pragma unroll
                for (int n2 = 0; n2 < 2; n2++) {
                    bf16x8 vf = *(const bf16x8*)(lds + VB + (((h*3+s2)*2+n2)*4+kgl)*256 + lr*16);
                    oacc[j][n2] = MFMA(pa, vf, oacc[j][n2]);
                }
            }
        }
    }
    __syncthreads();                               // (4) scratch dead

    // ---- P5: O -> XB planes (X layout), bf16 ----
    #pragma unroll
    for (int j = 0; j < 3; j++)
        #pragma unroll
        for (int n2 = 0; n2 < 2; n2++) {
            const int dcol = h*32 + n2*16 + lr;
            const int kc   = dcol >> 3;            // 0..31
            const int irow = ib + j;
            char* base = lds + XB + (((kc>>2)*6 + irow)*4 + (kc&3))*256 + (dcol&7)*2;
            #pragma unroll
            for (int r = 0; r < 4; r++)
                *(ushort*)(base + (kgl*4+r)*16) = to_bf16(oacc[j][n2][r]);
        }
    __syncthreads();                               // (5)

    // ---- P6: wo GEMM: M = t (O planes in XB), N = d (tile wv) -> out ----
    {
        const ushort* Wo = W + 3*WSZ;
        bf16x8 wf[8];
        #pragma unroll
        for (int ks = 0; ks < 8; ks++)
            wf[ks] = *(const bf16x8*)(Wo + ((size_t)(ks*4+kgl)*256 + wv*16 + lr)*8);
        f32x4 a2[6];
        #pragma unroll
        for (int mt = 0; mt < 6; mt++) a2[mt] = (f32x4)0.f;
        #pragma unroll
        for (int ks = 0; ks < 8; ks++)
            #pragma unroll
            for (int mt = 0; mt < 6; mt++) {
                bf16x8 oa = *(const bf16x8*)(lds + XB + ((ks*6+mt)*4+kgl)*256 + lr*16);
                a2[mt] = MFMA(oa, wf[ks], a2[mt]);
            }
        const float bod = bo[wv*16 + lr];
        #pragma unroll
        for (int mt = 0; mt < 6; mt++)
            #pragma unroll
            for (int r = 0; r < 4; r++) {
                const int t = mt*16 + kgl*4 + r;
                out[((size_t)(bn*T_ + t))*D_ + wv*16 + lr] = a2[mt][r] + bod;
            }
    }
}

// ---------------------------------------------------------------------------
extern "C" void kernel_launch(void* const* d_in, const int* in_sizes, int n_in,
                              void* d_out, int out_size, void* d_ws, size_t ws_size,
                              hipStream_t stream)
{
    const float* query = (const float*)d_in[0];
    const float* key   = (const float*)d_in[1];
    const float* value = (const float*)d_in[2];
    // d_in[3..5]: pattern_matrix, Wp, bp -- mathematically a no-op (mask == 1)
    const float* Wq = (const float*)d_in[6];
    const float* bq = (const float*)d_in[7];
    const float* Wk = (const float*)d_in[8];
    const float* bk = (const float*)d_in[9];
    const float* Wv = (const float*)d_in[10];
    const float* bv = (const float*)d_in[11];
    const float* Wo = (const float*)d_in[12];
    const float* bo = (const float*)d_in[13];

    float*  out = (float*)d_out;
    ushort* whi = (ushort*)d_ws;   // 4 matrices, chunked bf16: 512 KB

    splitw_kernel<<<dim3(128), 256, 0, stream>>>(Wq, Wk, Wv, Wo, whi);
    mega_kernel<<<dim3(BN_), 1024, 0, stream>>>(
        query, key, value, whi, bq, bk, bv, bo, out);
}